// Round 1
// baseline (102.157 us; speedup 1.0000x reference)
//
#include <hip/hip_runtime.h>
#include <hip/hip_bf16.h>

// NT-Xent loss, N=4096, Z=128, T=0.5.
// Pipeline:
//  k_zero:      denom[8192] = 0
//  k_normalize: row-normalize z1/z2 (fp32), quantize to bf16 nreps[8192x128],
//               exact fp32 pair-cosines pos[4096]
//  k_simsum:    denom[i] = sum_{j != i} exp(2 * sim_ij)  via bf16 MFMA GEMM
//               with fused exp + row-sum epilogue (no LDS, no barriers;
//               full-K A-frags persist in registers, K=128 = 4 MFMA steps)
//  k_finish:    out = (sum_i log denom_i - 4 * sum_p pos_p) / 8192

#define N_PAIRS 4096
#define ZDIM    128
#define NROWS   8192
// exp(sim/T) = exp2(sim * (1/T) * log2(e)) ; 1/T = 2
#define EXP_SCALE 2.8853900817779268f

typedef __bf16 bf16x8 __attribute__((ext_vector_type(8)));
typedef float  floatx4 __attribute__((ext_vector_type(4)));

__global__ __launch_bounds__(256) void k_zero(float* __restrict__ denom) {
    int i = blockIdx.x * 256 + threadIdx.x;
    if (i < NROWS) denom[i] = 0.0f;
}

__global__ __launch_bounds__(256) void k_normalize(
    const float* __restrict__ z1, const float* __restrict__ z2,
    __hip_bfloat16* __restrict__ nreps, float* __restrict__ pos)
{
    const int w = threadIdx.x >> 6;
    const int lane = threadIdx.x & 63;
    const int p = blockIdx.x * 4 + w;            // pair index, < 4096
    const float2 a = ((const float2*)(z1 + (size_t)p * ZDIM))[lane];
    const float2 b = ((const float2*)(z2 + (size_t)p * ZDIM))[lane];
    float s1 = a.x * a.x + a.y * a.y;
    float s2 = b.x * b.x + b.y * b.y;
    float d  = a.x * b.x + a.y * b.y;
    #pragma unroll
    for (int off = 1; off < 64; off <<= 1) {
        s1 += __shfl_xor(s1, off, 64);
        s2 += __shfl_xor(s2, off, 64);
        d  += __shfl_xor(d,  off, 64);
    }
    const float n1 = fmaxf(sqrtf(s1), 1e-8f);
    const float n2 = fmaxf(sqrtf(s2), 1e-8f);
    const float i1 = 1.0f / n1, i2 = 1.0f / n2;
    float2 na; na.x = a.x * i1; na.y = a.y * i1;
    float2 nb; nb.x = b.x * i2; nb.y = b.y * i2;
    ((__hip_bfloat162*)(nreps + (size_t)p * ZDIM))[lane] = __float22bfloat162_rn(na);
    ((__hip_bfloat162*)(nreps + (size_t)(p + N_PAIRS) * ZDIM))[lane] = __float22bfloat162_rn(nb);
    if (lane == 0) pos[p] = d * i1 * i2;
}

// Block: 256 thr = 4 waves in 2x2; block tile = 128 rows x 1024 cols.
// grid = 64 row-tiles * 8 col-slabs = 512 blocks = 2/CU.
__global__ __launch_bounds__(256, 2) void k_simsum(
    const __hip_bfloat16* __restrict__ nreps, float* __restrict__ denom)
{
    const int tid  = threadIdx.x;
    const int lane = tid & 63;
    const int w    = tid >> 6;
    const int wr   = w >> 1, wc = w & 1;
    const int rt   = blockIdx.x >> 3;   // row tile [0,64)
    const int cs   = blockIdx.x & 7;    // col slab [0,8)
    const int q    = lane >> 4;         // quad 0..3 (selects k-chunk of 8)
    const int l16  = lane & 15;

    // ---- persistent A fragments: wave's 64 rows x full K=128 (64 VGPRs) ----
    // A-operand layout: A[m = lane&15][k = q*8 + j]
    const int arow = rt * 128 + wr * 64 + l16;           // + mt*16
    const __hip_bfloat16* Abase = nreps + (size_t)arow * ZDIM + q * 8;
    bf16x8 afrag[4][4];
    #pragma unroll
    for (int mt = 0; mt < 4; ++mt)
        #pragma unroll
        for (int ks = 0; ks < 4; ++ks)
            afrag[mt][ks] = *(const bf16x8*)(Abase + mt * 16 * ZDIM + ks * 32);

    float rowsum[4][4];
    #pragma unroll
    for (int mt = 0; mt < 4; ++mt)
        #pragma unroll
        for (int r = 0; r < 4; ++r) rowsum[mt][r] = 0.0f;

    const int colbase = cs * 1024 + wc * 64 + l16;       // + it*128 + nt*16
    const int growb   = rt * 128 + wr * 64 + q * 4;      // + mt*16 + r

    for (int it = 0; it < 8; ++it) {
        floatx4 acc[4][4];
        #pragma unroll
        for (int mt = 0; mt < 4; ++mt)
            #pragma unroll
            for (int nt = 0; nt < 4; ++nt) {
                acc[mt][nt].x = 0.f; acc[mt][nt].y = 0.f;
                acc[mt][nt].z = 0.f; acc[mt][nt].w = 0.f;
            }
        // B-operand layout: B[k = q*8 + j][n = lane&15]; row-major source,
        // so B-frag load pattern is identical to A-frag (sim = A * A^T).
        const __hip_bfloat16* Bbase =
            nreps + (size_t)(colbase + it * 128) * ZDIM + q * 8;
        #pragma unroll
        for (int ks = 0; ks < 4; ++ks) {
            bf16x8 bfrag[4];
            #pragma unroll
            for (int nt = 0; nt < 4; ++nt)
                bfrag[nt] = *(const bf16x8*)(Bbase + nt * 16 * ZDIM + ks * 32);
            #pragma unroll
            for (int mt = 0; mt < 4; ++mt)
                #pragma unroll
                for (int nt = 0; nt < 4; ++nt)
                    acc[mt][nt] = __builtin_amdgcn_mfma_f32_16x16x32_bf16(
                        afrag[mt][ks], bfrag[nt], acc[mt][nt], 0, 0, 0);
        }
        // ---- fused epilogue: exp + row-sum, diagonal masked ----
        // C/D layout: col = lane&15, row = q*4 + reg  (m89/m91 verified)
        const int gcolb = cs * 1024 + it * 128 + wc * 64 + l16;
        #pragma unroll
        for (int mt = 0; mt < 4; ++mt) {
            #pragma unroll
            for (int nt = 0; nt < 4; ++nt) {
                const int gcol = gcolb + nt * 16;
                #pragma unroll
                for (int r = 0; r < 4; ++r) {
                    const int grow = growb + mt * 16 + r;
                    const float e = __expf(acc[mt][nt][r] * 2.0f);
                    rowsum[mt][r] += (grow == gcol) ? 0.0f : e;
                }
            }
        }
    }

    // reduce across the 16 lanes holding the same row (cols 0..15 of frag)
    #pragma unroll
    for (int mt = 0; mt < 4; ++mt)
        #pragma unroll
        for (int r = 0; r < 4; ++r) {
            float s = rowsum[mt][r];
            s += __shfl_xor(s, 1, 64);
            s += __shfl_xor(s, 2, 64);
            s += __shfl_xor(s, 4, 64);
            s += __shfl_xor(s, 8, 64);
            rowsum[mt][r] = s;
        }
    if (l16 == 0) {
        #pragma unroll
        for (int mt = 0; mt < 4; ++mt)
            #pragma unroll
            for (int r = 0; r < 4; ++r) {
                const int grow = rt * 128 + wr * 64 + mt * 16 + q * 4 + r;
                atomicAdd(&denom[grow], rowsum[mt][r]);
            }
    }
}

__global__ __launch_bounds__(1024) void k_finish(
    const float* __restrict__ denom, const float* __restrict__ pos,
    float* __restrict__ out)
{
    __shared__ float red[1024];
    const int t = threadIdx.x;
    float s = 0.0f;
    for (int i = t; i < NROWS; i += 1024) s += __logf(denom[i]);
    float p = 0.0f;
    for (int i = t; i < N_PAIRS; i += 1024) p += pos[i];
    red[t] = s - 4.0f * p;   // sum_i pos_i/T over 2N rows = 4 * sum_p cos_p
    __syncthreads();
    for (int off = 512; off > 0; off >>= 1) {
        if (t < off) red[t] += red[t + off];
        __syncthreads();
    }
    if (t == 0) out[0] = red[0] / (float)NROWS;
}

extern "C" void kernel_launch(void* const* d_in, const int* in_sizes, int n_in,
                              void* d_out, int out_size, void* d_ws, size_t ws_size,
                              hipStream_t stream) {
    const float* z1 = (const float*)d_in[0];
    const float* z2 = (const float*)d_in[1];
    float* out = (float*)d_out;

    char* ws = (char*)d_ws;
    __hip_bfloat16* nreps = (__hip_bfloat16*)ws;               // 2 MB
    float* denom = (float*)(ws + (size_t)NROWS * ZDIM * 2);    // 32 KB
    float* pos   = denom + NROWS;                              // 16 KB

    k_zero<<<NROWS / 256, 256, 0, stream>>>(denom);
    k_normalize<<<N_PAIRS / 4, 256, 0, stream>>>(z1, z2, nreps, pos);
    k_simsum<<<512, 256, 0, stream>>>(nreps, denom);
    k_finish<<<1, 1024, 0, stream>>>(denom, pos, out);
}